// Round 12
// baseline (4296.506 us; speedup 1.0000x reference)
//
#include <hip/hip_runtime.h>

// Problem dims (fixed)
#define S_TOK 4096
#define H_DIM 4096
#define NOUT  12288   // DQ + 2*DKV
#define KBIG  4480    // H_DIM + 8*48  (divisible by 64)
#define NADP  8
#define RANK  16
#define NT    (KBIG / 64)   // 70 K-tiles

typedef __bf16 bf16x8 __attribute__((ext_vector_type(8)));
typedef float  f32x4  __attribute__((ext_vector_type(4)));

__device__ __forceinline__ unsigned short f2bf(float f) {
  union { float f; unsigned int u; } v; v.f = f;
  unsigned int u = v.u;
  unsigned int r = (u + 0x7FFFu + ((u >> 16) & 1u)) >> 16;  // RNE
  return (unsigned short)r;
}

__device__ __forceinline__ void gload_lds16(const void* g, void* l) {
  __builtin_amdgcn_global_load_lds(
      (const __attribute__((address_space(1))) void*)g,
      (__attribute__((address_space(3))) void*)l,
      16, 0, 0);
}

// ---------------------------------------------------------------------------
// Fused prep: one launch, blockIdx-dispatched independent jobs (R8-proven).
#define WT_BLOCKS 12288
#define CX_BLOCKS 4096
#define TA_BLOCKS 256
#define BF_BLOCKS 1536
__global__ __launch_bounds__(256) void prep_fused(
    const float* __restrict__ W, const float* __restrict__ x,
    const float* __restrict__ A, const float* __restrict__ Bq,
    const float* __restrict__ Bkv, unsigned short* __restrict__ WbigT,
    unsigned short* __restrict__ xbig, unsigned short* __restrict__ AT) {
  __shared__ float smem[128 * 49];   // 25 KB, reused per job
  const int b = blockIdx.x;
  const int tid = threadIdx.x;

  if (b < WT_BLOCKS) {
    // ---- W transpose: n0 = (b%192)*64, k0 = (b/192)*64
    float (*tile)[65] = (float(*)[65])smem;
    const int n0 = (b % 192) * 64;
    const int k0 = (b / 192) * 64;
    const int c = tid & 63;
    const int rb = tid >> 6;
#pragma unroll
    for (int p = 0; p < 16; ++p) {
      int r = p * 4 + rb;
      tile[r][c] = W[(size_t)(k0 + r) * NOUT + n0 + c];
    }
    __syncthreads();
#pragma unroll
    for (int p = 0; p < 16; ++p) {
      int nr = p * 4 + rb;
      WbigT[(size_t)(n0 + nr) * KBIG + k0 + c] = f2bf(tile[c][nr]);
    }
  } else if (b < WT_BLOCKS + CX_BLOCKS) {
    // ---- x convert (vectorized)
    const int t = b - WT_BLOCKS;
    const float4* xr = (const float4*)(x + (size_t)t * H_DIM);
    ushort4* o = (ushort4*)(xbig + (size_t)t * KBIG);
#pragma unroll
    for (int p = 0; p < 4; ++p) {
      float4 v = xr[p * 256 + tid];
      ushort4 u;
      u.x = f2bf(v.x); u.y = f2bf(v.y); u.z = f2bf(v.z); u.w = f2bf(v.w);
      o[p * 256 + tid] = u;
    }
  } else if (b < WT_BLOCKS + CX_BLOCKS + TA_BLOCKS) {
    // ---- A transpose: adapter a, 128 h-rows
    const int bb = b - (WT_BLOCKS + CX_BLOCKS);
    const int a = bb >> 5;
    const int h0 = (bb & 31) * 128;
    float (*t)[49] = (float(*)[49])smem;
    const float* src = A + ((size_t)a * H_DIM + h0) * 48;
#pragma unroll
    for (int e = 0; e < 24; ++e) {
      int idx = e * 256 + tid;            // 0..6143
      t[idx / 48][idx % 48] = src[idx];
    }
    __syncthreads();
#pragma unroll
    for (int e = 0; e < 24; ++e) {
      int idx = e * 256 + tid;
      int j = idx >> 7;                   // 0..47
      int c = idx & 127;
      AT[(size_t)(a * 48 + j) * H_DIM + h0 + c] = f2bf(t[c][j]);
    }
  } else {
    // ---- Bfull ext columns: 8 n-rows per block (3072 elems, 12/thread)
    const int bb = b - (WT_BLOCKS + CX_BLOCKS + TA_BLOCKS);
#pragma unroll
    for (int e = 0; e < 12; ++e) {
      int idx = e * 256 + tid;            // 0..3071
      int n = bb * 8 + (idx / 384);
      int c = idx % 384;
      int a = c / 48, j = c % 48;
      float v = 0.0f;
      if (j < 16) {
        if (n < 4096) v = Bq[(size_t)(a * RANK + j) * 4096 + n];
      } else if (j < 32) {
        if (n >= 4096 && n < 8192) v = Bkv[(size_t)(a * RANK + (j - 16)) * 8192 + (n - 4096)];
      } else {
        if (n >= 8192) v = Bkv[(size_t)(a * RANK + (j - 32)) * 8192 + (n - 4096)];
      }
      WbigT[(size_t)n * KBIG + H_DIM + c] = f2bf(v);
    }
  }
}

// ---------------------------------------------------------------------------
// K2b: xa_all = x @ A_all  (M=4096, N=384, K=4096), epilogue scatters
// per-token adapter selection into xbig ext columns.
// 128x64 tile -> grid (6,32)=192 blocks (R8-proven 45us).
__global__ __launch_bounds__(256) void xa_gemm_scatter(
    const unsigned short* __restrict__ Xb, const unsigned short* __restrict__ AT,
    const int* __restrict__ widx, unsigned short* __restrict__ xbig) {
  __shared__ __align__(16) unsigned char lds[16384 + 8192];  // As 128x64, Bs 64x64
  const int tid = threadIdx.x;
  const int w = tid >> 6, l = tid & 63;
  const int wm = w >> 1, wn = w & 1;
  const int lr = l & 15, hi = l >> 4;
  const int innsw = (lr & 7) << 4;
  const int m0 = blockIdx.y * 128;   // token tile
  const int n0 = blockIdx.x * 64;    // j tile

  f32x4 acc[4][2];
  const f32x4 fzero = {0.f, 0.f, 0.f, 0.f};
#pragma unroll
  for (int mf = 0; mf < 4; ++mf)
#pragma unroll
    for (int nf = 0; nf < 2; ++nf) acc[mf][nf] = fzero;

  for (int kt = 0; kt < H_DIM / 64; ++kt) {
    __syncthreads();
    const int kb = kt * 64;
#pragma unroll
    for (int ld = 0; ld < 4; ++ld) {
      int d = (ld * 256 + tid) * 16;
      int row = d >> 7;
      int colb = (d & 127) ^ ((row & 7) << 4);
      gload_lds16((const char*)Xb + (size_t)(m0 + row) * (KBIG * 2) + kb * 2 + colb,
                  &lds[d]);
    }
#pragma unroll
    for (int ld = 0; ld < 2; ++ld) {
      int d = (ld * 256 + tid) * 16;
      int row = d >> 7;
      int colb = (d & 127) ^ ((row & 7) << 4);
      gload_lds16((const char*)AT + (size_t)(n0 + row) * (H_DIM * 2) + kb * 2 + colb,
                  &lds[16384 + d]);
    }
    __syncthreads();
#pragma unroll
    for (int kk = 0; kk < 2; ++kk) {
      bf16x8 af[4], bfr[2];
#pragma unroll
      for (int mf = 0; mf < 4; ++mf)
        af[mf] = *(const bf16x8*)(lds + (wm * 64 + mf * 16 + lr) * 128 +
                                  ((kk * 64 + hi * 16) ^ innsw));
#pragma unroll
      for (int nf = 0; nf < 2; ++nf)
        bfr[nf] = *(const bf16x8*)(lds + 16384 + (wn * 32 + nf * 16 + lr) * 128 +
                                   ((kk * 64 + hi * 16) ^ innsw));
#pragma unroll
      for (int mf = 0; mf < 4; ++mf)
#pragma unroll
        for (int nf = 0; nf < 2; ++nf)
          acc[mf][nf] = __builtin_amdgcn_mfma_f32_16x16x32_bf16(
              af[mf], bfr[nf], acc[mf][nf], 0, 0, 0);
    }
  }
  // scatter epilogue: keep only the token's own adapter block, else 0
  const int r4 = hi * 4;
#pragma unroll
  for (int mf = 0; mf < 4; ++mf)
#pragma unroll
    for (int r = 0; r < 4; ++r) {
      const int t = m0 + wm * 64 + mf * 16 + r4 + r;
      const int a = widx[t];
#pragma unroll
      for (int nf = 0; nf < 2; ++nf) {
        const int col = n0 + wn * 32 + nf * 16 + lr;   // j in [0,384)
        float v = (col / 48 == a) ? acc[mf][nf][r] : 0.0f;
        xbig[(size_t)t * KBIG + H_DIM + col] = f2bf(v);
      }
    }
}

// ---------------------------------------------------------------------------
// K3: 256x256-tile bf16 GEMM, SINGLE-BUFFER in-place staging -> 64KB LDS
// -> 2 blocks/CU (cross-block TLP hides LDS<->MFMA serialization).
// Zigzag quads + register retention: each LDS half is dead (regs hold it)
// right after its phase's reads, so tile t+1's half is staged in place one
// phase later. Stages: P1:{A0',B0'} P2:{B1'} P3:{A1'}. Waits (FIFO-derived,
// never 0, 2-8 in flight): vmcnt(2)@P0end, vmcnt(4)@P1end, vmcnt(4)@P3end.
// Race-free: any P(k+1) stage issues after the Pk-end barrier, which orders
// it after ALL waves' Pk ds_reads (lgkm before MFMA before barrier).
// XCD 8x12 rectangle swizzle kept (FETCH 900->323 MB, R11-verified).
__global__ __launch_bounds__(512, 4) void gemm_bf16_ip(
    const unsigned short* __restrict__ Xb, const unsigned short* __restrict__ Wt,
    float* __restrict__ out) {
  __shared__ __align__(16) unsigned char lds[4 * 16384];  // halves A0,B0,B1,A1

  const int tid = threadIdx.x;
  const int w   = tid >> 6;
  const int l   = tid & 63;
  const int wm  = w >> 2;        // 0..1
  const int wn  = w & 3;         // 0..3
  const int lr  = l & 15;
  const int hi  = l >> 4;
  const int innsw = (lr & 7) << 4;   // read-side XOR swizzle bits

  // XCD 8x12 rectangle swizzle: xcd r -> rect (r>>2, r&3); local col-major
  const int id  = blockIdx.x;
  const int r8  = id & 7;            // XCD
  const int loc = id >> 3;           // 0..95
  const int lm  = loc & 7;           // 0..7  (bm within rect)
  const int ln  = loc >> 3;          // 0..11 (bn within rect)
  const int bm  = (r8 >> 2) * 8 + lm;
  const int bn  = (r8 & 3) * 12 + ln;
  const int m0 = bm * 256, n0 = bn * 256;

  // stage one 128x64 half-tile into LDS half h (linear dest, preswz source)
  auto stage = [&](int h, const unsigned short* G, int row0, int kb) {
    unsigned char* lb = &lds[h * 16384];
    const char* gb = (const char*)G;
#pragma unroll
    for (int ld = 0; ld < 2; ++ld) {
      int d = (ld * 512 + tid) * 16;            // linear LDS dest byte
      int row = d >> 7;                          // 0..127
      int colb = (d & 127) ^ ((row & 7) << 4);   // swizzled source col (bytes)
      gload_lds16(gb + (size_t)(row0 + row) * (KBIG * 2) + kb * 2 + colb,
                  lb + d);
    }
  };
  auto readF = [&](int h, int rowloc, int kk) -> bf16x8 {
    const unsigned char* lb = &lds[h * 16384];
    int ph = rowloc * 128 + ((kk * 64 + hi * 16) ^ innsw);
    return *(const bf16x8*)(lb + ph);
  };

  f32x4 acc[4][4][2];   // [quad][mf][nf]
  const f32x4 fzero = {0.f, 0.f, 0.f, 0.f};
#pragma unroll
  for (int q = 0; q < 4; ++q)
#pragma unroll
    for (int mf = 0; mf < 4; ++mf)
#pragma unroll
      for (int nf = 0; nf < 2; ++nf) acc[q][mf][nf] = fzero;

  bf16x8 a_[4][2];   // current A-half fragments (A0 in P0/P1, A1 in P2/P3)
  bf16x8 b0_[2][2];  // B half 0 fragments (live P0..P3)
  bf16x8 b1_[2][2];  // B half 1 fragments (live P1..P2)

#define MFMA_QUAD(Q, BSRC)                                                   \
    _Pragma("unroll") for (int kk = 0; kk < 2; ++kk)                         \
      _Pragma("unroll") for (int mf = 0; mf < 4; ++mf)                       \
        _Pragma("unroll") for (int nf = 0; nf < 2; ++nf)                     \
          acc[Q][mf][nf] = __builtin_amdgcn_mfma_f32_16x16x32_bf16(          \
              a_[mf][kk], BSRC[nf][kk], acc[Q][mf][nf], 0, 0, 0)

  // prologue: stage tile 0 halves A0,B0,B1,A1 (8 loads outstanding)
  stage(0, Xb, m0,       0);
  stage(1, Wt, n0,       0);
  stage(2, Wt, n0 + 128, 0);
  stage(3, Xb, m0 + 128, 0);
  asm volatile("s_waitcnt vmcnt(4)" ::: "memory");   // A0,B0 landed
  __builtin_amdgcn_s_barrier();
  // loop invariant at P0 entry: queue = [B1(t), A1(t)] (4 loads)

  for (int t = 0; t < NT; ++t) {
    const int tn = (t + 1 < NT) ? (t + 1) : t;   // dummy re-stage on last tile
    const int kb_next = tn * 64;

    // P0: read A0,B0; quad (M0,N0). No stage.
#pragma unroll
    for (int mf = 0; mf < 4; ++mf)
#pragma unroll
      for (int kk = 0; kk < 2; ++kk)
        a_[mf][kk] = readF(0, wm * 64 + mf * 16 + lr, kk);
#pragma unroll
    for (int nf = 0; nf < 2; ++nf)
#pragma unroll
      for (int kk = 0; kk < 2; ++kk)
        b0_[nf][kk] = readF(1, wn * 32 + nf * 16 + lr, kk);
    __builtin_amdgcn_s_setprio(1);
    MFMA_QUAD(0, b0_);
    __builtin_amdgcn_s_setprio(0);
    asm volatile("s_waitcnt vmcnt(2)" ::: "memory");   // B1(t) landed
    __builtin_amdgcn_s_barrier();

    // P1: read B1; stage A0',B0' (A0/B0 LDS dead); quad (M0,N1).
#pragma unroll
    for (int nf = 0; nf < 2; ++nf)
#pragma unroll
      for (int kk = 0; kk < 2; ++kk)
        b1_[nf][kk] = readF(2, wn * 32 + nf * 16 + lr, kk);
    stage(0, Xb, m0, kb_next);
    stage(1, Wt, n0, kb_next);
    __builtin_amdgcn_s_setprio(1);
    MFMA_QUAD(1, b1_);
    __builtin_amdgcn_s_setprio(0);
    asm volatile("s_waitcnt vmcnt(4)" ::: "memory");   // A1(t) landed
    __builtin_amdgcn_s_barrier();

    // P2: read A1; stage B1' (B1 LDS dead); quad (M1,N1). No wait.
#pragma unroll
    for (int mf = 0; mf < 4; ++mf)
#pragma unroll
      for (int kk = 0; kk < 2; ++kk)
        a_[mf][kk] = readF(3, wm * 64 + mf * 16 + lr, kk);
    stage(2, Wt, n0 + 128, kb_next);
    __builtin_amdgcn_s_setprio(1);
    MFMA_QUAD(2, b1_);
    __builtin_amdgcn_s_setprio(0);
    __builtin_amdgcn_s_barrier();

    // P3: stage A1' (A1 LDS dead); quad (M1,N0). No reads.
    stage(3, Xb, m0 + 128, kb_next);
    __builtin_amdgcn_s_setprio(1);
    MFMA_QUAD(3, b0_);
    __builtin_amdgcn_s_setprio(0);
    asm volatile("s_waitcnt vmcnt(4)" ::: "memory");   // A0',B0' landed
    __builtin_amdgcn_s_barrier();
  }
#undef MFMA_QUAD

  // epilogue: C/D mapping col = lane&15, row = (lane>>4)*4 + reg
  const int r4 = hi * 4;
  constexpr int QM[4] = {0, 0, 1, 1};
  constexpr int QN[4] = {0, 1, 1, 0};
#pragma unroll
  for (int q = 0; q < 4; ++q)
#pragma unroll
    for (int mf = 0; mf < 4; ++mf)
#pragma unroll
      for (int nf = 0; nf < 2; ++nf) {
        const int row = m0 + QM[q] * 128 + wm * 64 + mf * 16 + r4;
        const int col = n0 + QN[q] * 128 + wn * 32 + nf * 16 + lr;
#pragma unroll
        for (int r = 0; r < 4; ++r)
          out[(size_t)(row + r) * NOUT + col] = acc[q][mf][nf][r];
      }
}

// ---------------------------------------------------------------------------
extern "C" void kernel_launch(void* const* d_in, const int* in_sizes, int n_in,
                              void* d_out, int out_size, void* d_ws, size_t ws_size,
                              hipStream_t stream) {
  const float* x    = (const float*)d_in[0];
  const int*   widx = (const int*)d_in[1];
  const float* W    = (const float*)d_in[2];
  const float* Aq   = (const float*)d_in[3];
  const float* Bq   = (const float*)d_in[4];
  const float* Bkv  = (const float*)d_in[5];
  float* out = (float*)d_out;

  unsigned short* xbig  = (unsigned short*)d_ws;
  unsigned short* WbigT = (unsigned short*)((char*)d_ws + (size_t)S_TOK * KBIG * 2);
  unsigned short* AT    = (unsigned short*)((char*)d_ws + (size_t)S_TOK * KBIG * 2
                                            + (size_t)NOUT * KBIG * 2);

  hipLaunchKernelGGL(prep_fused, dim3(WT_BLOCKS + CX_BLOCKS + TA_BLOCKS + BF_BLOCKS),
                     dim3(256), 0, stream, W, x, Aq, Bq, Bkv, WbigT, xbig, AT);
  hipLaunchKernelGGL(xa_gemm_scatter, dim3(6, S_TOK / 128), dim3(256), 0, stream,
                     xbig, AT, widx, xbig);
  hipLaunchKernelGGL(gemm_bf16_ip, dim3(768), dim3(512), 0, stream, xbig, WbigT, out);
}

// Round 13
// 482.389 us; speedup vs baseline: 8.9067x; 8.9067x over previous
//
#include <hip/hip_runtime.h>

// Problem dims (fixed)
#define S_TOK 4096
#define H_DIM 4096
#define NOUT  12288   // DQ + 2*DKV
#define KBIG  4480    // H_DIM + 8*48  (divisible by 64)
#define NADP  8
#define RANK  16
#define NT    (KBIG / 64)   // 70 K-tiles

typedef __bf16 bf16x8 __attribute__((ext_vector_type(8)));
typedef float  f32x4  __attribute__((ext_vector_type(4)));

__device__ __forceinline__ unsigned short f2bf(float f) {
  union { float f; unsigned int u; } v; v.f = f;
  unsigned int u = v.u;
  unsigned int r = (u + 0x7FFFu + ((u >> 16) & 1u)) >> 16;  // RNE
  return (unsigned short)r;
}

__device__ __forceinline__ void gload_lds16(const void* g, void* l) {
  __builtin_amdgcn_global_load_lds(
      (const __attribute__((address_space(1))) void*)g,
      (__attribute__((address_space(3))) void*)l,
      16, 0, 0);
}

// ---------------------------------------------------------------------------
// Fused prep: one launch, blockIdx-dispatched independent jobs (R8-proven).
#define WT_BLOCKS 12288
#define CX_BLOCKS 4096
#define TA_BLOCKS 256
#define BF_BLOCKS 1536
__global__ __launch_bounds__(256) void prep_fused(
    const float* __restrict__ W, const float* __restrict__ x,
    const float* __restrict__ A, const float* __restrict__ Bq,
    const float* __restrict__ Bkv, unsigned short* __restrict__ WbigT,
    unsigned short* __restrict__ xbig, unsigned short* __restrict__ AT) {
  __shared__ float smem[128 * 49];   // 25 KB, reused per job
  const int b = blockIdx.x;
  const int tid = threadIdx.x;

  if (b < WT_BLOCKS) {
    // ---- W transpose: n0 = (b%192)*64, k0 = (b/192)*64
    float (*tile)[65] = (float(*)[65])smem;
    const int n0 = (b % 192) * 64;
    const int k0 = (b / 192) * 64;
    const int c = tid & 63;
    const int rb = tid >> 6;
#pragma unroll
    for (int p = 0; p < 16; ++p) {
      int r = p * 4 + rb;
      tile[r][c] = W[(size_t)(k0 + r) * NOUT + n0 + c];
    }
    __syncthreads();
#pragma unroll
    for (int p = 0; p < 16; ++p) {
      int nr = p * 4 + rb;
      WbigT[(size_t)(n0 + nr) * KBIG + k0 + c] = f2bf(tile[c][nr]);
    }
  } else if (b < WT_BLOCKS + CX_BLOCKS) {
    // ---- x convert (vectorized)
    const int t = b - WT_BLOCKS;
    const float4* xr = (const float4*)(x + (size_t)t * H_DIM);
    ushort4* o = (ushort4*)(xbig + (size_t)t * KBIG);
#pragma unroll
    for (int p = 0; p < 4; ++p) {
      float4 v = xr[p * 256 + tid];
      ushort4 u;
      u.x = f2bf(v.x); u.y = f2bf(v.y); u.z = f2bf(v.z); u.w = f2bf(v.w);
      o[p * 256 + tid] = u;
    }
  } else if (b < WT_BLOCKS + CX_BLOCKS + TA_BLOCKS) {
    // ---- A transpose: adapter a, 128 h-rows
    const int bb = b - (WT_BLOCKS + CX_BLOCKS);
    const int a = bb >> 5;
    const int h0 = (bb & 31) * 128;
    float (*t)[49] = (float(*)[49])smem;
    const float* src = A + ((size_t)a * H_DIM + h0) * 48;
#pragma unroll
    for (int e = 0; e < 24; ++e) {
      int idx = e * 256 + tid;            // 0..6143
      t[idx / 48][idx % 48] = src[idx];
    }
    __syncthreads();
#pragma unroll
    for (int e = 0; e < 24; ++e) {
      int idx = e * 256 + tid;
      int j = idx >> 7;                   // 0..47
      int c = idx & 127;
      AT[(size_t)(a * 48 + j) * H_DIM + h0 + c] = f2bf(t[c][j]);
    }
  } else {
    // ---- Bfull ext columns: 8 n-rows per block (3072 elems, 12/thread)
    const int bb = b - (WT_BLOCKS + CX_BLOCKS + TA_BLOCKS);
#pragma unroll
    for (int e = 0; e < 12; ++e) {
      int idx = e * 256 + tid;            // 0..3071
      int n = bb * 8 + (idx / 384);
      int c = idx % 384;
      int a = c / 48, j = c % 48;
      float v = 0.0f;
      if (j < 16) {
        if (n < 4096) v = Bq[(size_t)(a * RANK + j) * 4096 + n];
      } else if (j < 32) {
        if (n >= 4096 && n < 8192) v = Bkv[(size_t)(a * RANK + (j - 16)) * 8192 + (n - 4096)];
      } else {
        if (n >= 8192) v = Bkv[(size_t)(a * RANK + (j - 32)) * 8192 + (n - 4096)];
      }
      WbigT[(size_t)n * KBIG + H_DIM + c] = f2bf(v);
    }
  }
}

// ---------------------------------------------------------------------------
// K2b: xa_all = x @ A_all  (M=4096, N=384, K=4096), epilogue scatters
// per-token adapter selection into xbig ext columns.
// 128x64 tile -> grid (6,32)=192 blocks (R8-proven 45us).
__global__ __launch_bounds__(256) void xa_gemm_scatter(
    const unsigned short* __restrict__ Xb, const unsigned short* __restrict__ AT,
    const int* __restrict__ widx, unsigned short* __restrict__ xbig) {
  __shared__ __align__(16) unsigned char lds[16384 + 8192];  // As 128x64, Bs 64x64
  const int tid = threadIdx.x;
  const int w = tid >> 6, l = tid & 63;
  const int wm = w >> 1, wn = w & 1;
  const int lr = l & 15, hi = l >> 4;
  const int innsw = (lr & 7) << 4;
  const int m0 = blockIdx.y * 128;   // token tile
  const int n0 = blockIdx.x * 64;    // j tile

  f32x4 acc[4][2];
  const f32x4 fzero = {0.f, 0.f, 0.f, 0.f};
#pragma unroll
  for (int mf = 0; mf < 4; ++mf)
#pragma unroll
    for (int nf = 0; nf < 2; ++nf) acc[mf][nf] = fzero;

  for (int kt = 0; kt < H_DIM / 64; ++kt) {
    __syncthreads();
    const int kb = kt * 64;
#pragma unroll
    for (int ld = 0; ld < 4; ++ld) {
      int d = (ld * 256 + tid) * 16;
      int row = d >> 7;
      int colb = (d & 127) ^ ((row & 7) << 4);
      gload_lds16((const char*)Xb + (size_t)(m0 + row) * (KBIG * 2) + kb * 2 + colb,
                  &lds[d]);
    }
#pragma unroll
    for (int ld = 0; ld < 2; ++ld) {
      int d = (ld * 256 + tid) * 16;
      int row = d >> 7;
      int colb = (d & 127) ^ ((row & 7) << 4);
      gload_lds16((const char*)AT + (size_t)(n0 + row) * (H_DIM * 2) + kb * 2 + colb,
                  &lds[16384 + d]);
    }
    __syncthreads();
#pragma unroll
    for (int kk = 0; kk < 2; ++kk) {
      bf16x8 af[4], bfr[2];
#pragma unroll
      for (int mf = 0; mf < 4; ++mf)
        af[mf] = *(const bf16x8*)(lds + (wm * 64 + mf * 16 + lr) * 128 +
                                  ((kk * 64 + hi * 16) ^ innsw));
#pragma unroll
      for (int nf = 0; nf < 2; ++nf)
        bfr[nf] = *(const bf16x8*)(lds + 16384 + (wn * 32 + nf * 16 + lr) * 128 +
                                   ((kk * 64 + hi * 16) ^ innsw));
#pragma unroll
      for (int mf = 0; mf < 4; ++mf)
#pragma unroll
        for (int nf = 0; nf < 2; ++nf)
          acc[mf][nf] = __builtin_amdgcn_mfma_f32_16x16x32_bf16(
              af[mf], bfr[nf], acc[mf][nf], 0, 0, 0);
    }
  }
  // scatter epilogue: keep only the token's own adapter block, else 0
  const int r4 = hi * 4;
#pragma unroll
  for (int mf = 0; mf < 4; ++mf)
#pragma unroll
    for (int r = 0; r < 4; ++r) {
      const int t = m0 + wm * 64 + mf * 16 + r4 + r;
      const int a = widx[t];
#pragma unroll
      for (int nf = 0; nf < 2; ++nf) {
        const int col = n0 + wn * 32 + nf * 16 + lr;   // j in [0,384)
        float v = (col / 48 == a) ? acc[mf][nf][r] : 0.0f;
        xbig[(size_t)t * KBIG + H_DIM + col] = f2bf(v);
      }
    }
}

// ---------------------------------------------------------------------------
// K3: 256x256-tile bf16 GEMM, 2 barriers per K-tile (R5/R8 structure, best
// measured 363-368us, 1242 TF). Register-retained fragments; counted vmcnt
// never 0; 32 MFMA per barrier region. Double-buffered 128KB LDS, 1 block/CU
// (structural: 256-tile needs ~252 regs/wave; 2 blocks/CU would cap at 128
// -> spills, R12-measured 12x regression). XCD 8x12 rectangle swizzle
// (FETCH 900->323 MB, R11-verified).
__global__ __launch_bounds__(512, 2) void gemm_bf16_8ph(
    const unsigned short* __restrict__ Xb, const unsigned short* __restrict__ Wt,
    float* __restrict__ out) {
  __shared__ __align__(16) unsigned char lds[2 * 2 * 2 * 16384];  // 128 KiB

  const int tid = threadIdx.x;
  const int w   = tid >> 6;
  const int l   = tid & 63;
  const int wm  = w >> 2;        // 0..1
  const int wn  = w & 3;         // 0..3
  const int lr  = l & 15;
  const int hi  = l >> 4;
  const int innsw = (lr & 7) << 4;   // read-side XOR swizzle bits

  // XCD 8x12 rectangle swizzle: xcd r -> rect (r>>2, r&3); local col-major
  const int id  = blockIdx.x;
  const int r8  = id & 7;            // XCD
  const int loc = id >> 3;           // 0..95
  const int lm  = loc & 7;           // 0..7  (bm within rect)
  const int ln  = loc >> 3;          // 0..11 (bn within rect)
  const int bm  = (r8 >> 2) * 8 + lm;
  const int bn  = (r8 & 3) * 12 + ln;
  const int m0 = bm * 256, n0 = bn * 256;

  auto stage = [&](int buf, int ab, int half, const unsigned short* G,
                   int row0, int kb) {
    unsigned char* lb = &lds[((((buf << 1) | ab) << 1) | half) * 16384];
    const char* gb = (const char*)G;
#pragma unroll
    for (int ld = 0; ld < 2; ++ld) {
      int d = (ld * 512 + tid) * 16;            // linear LDS dest byte
      int row = d >> 7;                          // 0..127
      int colb = (d & 127) ^ ((row & 7) << 4);   // swizzled source col (bytes)
      gload_lds16(gb + (size_t)(row0 + row) * (KBIG * 2) + kb * 2 + colb,
                  lb + d);
    }
  };
  auto readA = [&](int buf, int mq, int mf, int kk) -> bf16x8 {
    const unsigned char* lb = &lds[((((buf << 1) | 0) << 1) | mq) * 16384];
    int ph = (wm * 64 + mf * 16 + lr) * 128 + ((kk * 64 + hi * 16) ^ innsw);
    return *(const bf16x8*)(lb + ph);
  };
  auto readB = [&](int buf, int nq, int nf, int kk) -> bf16x8 {
    const unsigned char* lb = &lds[((((buf << 1) | 1) << 1) | nq) * 16384];
    int ph = (wn * 32 + nf * 16 + lr) * 128 + ((kk * 64 + hi * 16) ^ innsw);
    return *(const bf16x8*)(lb + ph);
  };

  f32x4 acc[4][4][2];   // [quad][mf][nf]
  const f32x4 fzero = {0.f, 0.f, 0.f, 0.f};
#pragma unroll
  for (int q = 0; q < 4; ++q)
#pragma unroll
    for (int mf = 0; mf < 4; ++mf)
#pragma unroll
      for (int nf = 0; nf < 2; ++nf) acc[q][mf][nf] = fzero;

  bf16x8 a_[4][2];   // current A-half fragments (A0 in H1, A1 in H2)
  bf16x8 b0_[2][2];  // B half 0 fragments (live whole iter)
  bf16x8 b1_[2][2];  // B half 1 fragments (live whole iter)

#define MFMA_QUAD(Q, BSRC)                                                   \
    _Pragma("unroll") for (int kk = 0; kk < 2; ++kk)                         \
      _Pragma("unroll") for (int mf = 0; mf < 4; ++mf)                       \
        _Pragma("unroll") for (int nf = 0; nf < 2; ++nf)                     \
          acc[Q][mf][nf] = __builtin_amdgcn_mfma_f32_16x16x32_bf16(          \
              a_[mf][kk], BSRC[nf][kk], acc[Q][mf][nf], 0, 0, 0)

  // prologue: stage tile 0 in order A0,B0,B1,A1 (8 loads outstanding)
  stage(0, 0, 0, Xb, m0,       0);
  stage(0, 1, 0, Wt, n0,       0);
  stage(0, 1, 1, Wt, n0 + 128, 0);
  stage(0, 0, 1, Xb, m0 + 128, 0);

  for (int t = 0; t < NT; ++t) {
    const int cur = t & 1, nxt = cur ^ 1;
    const int tn = (t + 1 < NT) ? (t + 1) : t;   // dummy re-stage on last tile
    const int kb_next = tn * 64;

    // iter top: A0,B0,B1 of buf[cur] landed (6 of 8 retired)
    asm volatile("s_waitcnt vmcnt(2)" ::: "memory");
    __builtin_amdgcn_s_barrier();

    // H1: read A0, B0, B1; stage next A0,B0; quads (M0,N0) + (M0,N1)
#pragma unroll
    for (int mf = 0; mf < 4; ++mf)
#pragma unroll
      for (int kk = 0; kk < 2; ++kk) a_[mf][kk] = readA(cur, 0, mf, kk);
#pragma unroll
    for (int nf = 0; nf < 2; ++nf)
#pragma unroll
      for (int kk = 0; kk < 2; ++kk) b0_[nf][kk] = readB(cur, 0, nf, kk);
#pragma unroll
    for (int nf = 0; nf < 2; ++nf)
#pragma unroll
      for (int kk = 0; kk < 2; ++kk) b1_[nf][kk] = readB(cur, 1, nf, kk);
    stage(nxt, 0, 0, Xb, m0, kb_next);
    stage(nxt, 1, 0, Wt, n0, kb_next);
    __builtin_amdgcn_s_setprio(1);
    MFMA_QUAD(0, b0_);
    MFMA_QUAD(1, b1_);
    __builtin_amdgcn_s_setprio(0);

    // mid: A1 of buf[cur] landed (2 old retired; 4 new still in flight)
    asm volatile("s_waitcnt vmcnt(4)" ::: "memory");
    __builtin_amdgcn_s_barrier();

    // H2: read A1; stage next B1,A1; quads (M1,N1) + (M1,N0)
#pragma unroll
    for (int mf = 0; mf < 4; ++mf)
#pragma unroll
      for (int kk = 0; kk < 2; ++kk) a_[mf][kk] = readA(cur, 1, mf, kk);
    stage(nxt, 1, 1, Wt, n0 + 128, kb_next);
    stage(nxt, 0, 1, Xb, m0 + 128, kb_next);
    __builtin_amdgcn_s_setprio(1);
    MFMA_QUAD(2, b1_);
    MFMA_QUAD(3, b0_);
    __builtin_amdgcn_s_setprio(0);
  }
#undef MFMA_QUAD

  // epilogue: C/D mapping col = lane&15, row = (lane>>4)*4 + reg
  const int r4 = hi * 4;
  constexpr int QM[4] = {0, 0, 1, 1};
  constexpr int QN[4] = {0, 1, 1, 0};
#pragma unroll
  for (int q = 0; q < 4; ++q)
#pragma unroll
    for (int mf = 0; mf < 4; ++mf)
#pragma unroll
      for (int nf = 0; nf < 2; ++nf) {
        const int row = m0 + QM[q] * 128 + wm * 64 + mf * 16 + r4;
        const int col = n0 + QN[q] * 128 + wn * 32 + nf * 16 + lr;
#pragma unroll
        for (int r = 0; r < 4; ++r)
          out[(size_t)(row + r) * NOUT + col] = acc[q][mf][nf][r];
      }
}

// ---------------------------------------------------------------------------
extern "C" void kernel_launch(void* const* d_in, const int* in_sizes, int n_in,
                              void* d_out, int out_size, void* d_ws, size_t ws_size,
                              hipStream_t stream) {
  const float* x    = (const float*)d_in[0];
  const int*   widx = (const int*)d_in[1];
  const float* W    = (const float*)d_in[2];
  const float* Aq   = (const float*)d_in[3];
  const float* Bq   = (const float*)d_in[4];
  const float* Bkv  = (const float*)d_in[5];
  float* out = (float*)d_out;

  unsigned short* xbig  = (unsigned short*)d_ws;
  unsigned short* WbigT = (unsigned short*)((char*)d_ws + (size_t)S_TOK * KBIG * 2);
  unsigned short* AT    = (unsigned short*)((char*)d_ws + (size_t)S_TOK * KBIG * 2
                                            + (size_t)NOUT * KBIG * 2);

  hipLaunchKernelGGL(prep_fused, dim3(WT_BLOCKS + CX_BLOCKS + TA_BLOCKS + BF_BLOCKS),
                     dim3(256), 0, stream, W, x, Aq, Bq, Bkv, WbigT, xbig, AT);
  hipLaunchKernelGGL(xa_gemm_scatter, dim3(6, S_TOK / 128), dim3(256), 0, stream,
                     xbig, AT, widx, xbig);
  hipLaunchKernelGGL(gemm_bf16_8ph, dim3(768), dim3(512), 0, stream, xbig, WbigT, out);
}

// Round 14
// 470.424 us; speedup vs baseline: 9.1333x; 1.0254x over previous
//
#include <hip/hip_runtime.h>

// Problem dims (fixed)
#define S_TOK 4096
#define H_DIM 4096
#define NOUT  12288   // DQ + 2*DKV
#define KBIG  4480    // H_DIM + 8*48  (divisible by 64)
#define NADP  8
#define RANK  16
#define NT    (KBIG / 64)   // 70 K-tiles

typedef __bf16 bf16x8 __attribute__((ext_vector_type(8)));
typedef float  f32x4  __attribute__((ext_vector_type(4)));

__device__ __forceinline__ unsigned short f2bf(float f) {
  union { float f; unsigned int u; } v; v.f = f;
  unsigned int u = v.u;
  unsigned int r = (u + 0x7FFFu + ((u >> 16) & 1u)) >> 16;  // RNE
  return (unsigned short)r;
}

__device__ __forceinline__ void gload_lds16(const void* g, void* l) {
  __builtin_amdgcn_global_load_lds(
      (const __attribute__((address_space(1))) void*)g,
      (__attribute__((address_space(3))) void*)l,
      16, 0, 0);
}

// ---------------------------------------------------------------------------
// Fused prep: one launch, blockIdx-dispatched independent jobs (R8-proven).
#define WT_BLOCKS 12288
#define CX_BLOCKS 4096
#define TA_BLOCKS 256
#define BF_BLOCKS 1536
__global__ __launch_bounds__(256) void prep_fused(
    const float* __restrict__ W, const float* __restrict__ x,
    const float* __restrict__ A, const float* __restrict__ Bq,
    const float* __restrict__ Bkv, unsigned short* __restrict__ WbigT,
    unsigned short* __restrict__ xbig, unsigned short* __restrict__ AT) {
  __shared__ float smem[128 * 49];   // 25 KB, reused per job
  const int b = blockIdx.x;
  const int tid = threadIdx.x;

  if (b < WT_BLOCKS) {
    // ---- W transpose: n0 = (b%192)*64, k0 = (b/192)*64
    float (*tile)[65] = (float(*)[65])smem;
    const int n0 = (b % 192) * 64;
    const int k0 = (b / 192) * 64;
    const int c = tid & 63;
    const int rb = tid >> 6;
#pragma unroll
    for (int p = 0; p < 16; ++p) {
      int r = p * 4 + rb;
      tile[r][c] = W[(size_t)(k0 + r) * NOUT + n0 + c];
    }
    __syncthreads();
#pragma unroll
    for (int p = 0; p < 16; ++p) {
      int nr = p * 4 + rb;
      WbigT[(size_t)(n0 + nr) * KBIG + k0 + c] = f2bf(tile[c][nr]);
    }
  } else if (b < WT_BLOCKS + CX_BLOCKS) {
    // ---- x convert (vectorized)
    const int t = b - WT_BLOCKS;
    const float4* xr = (const float4*)(x + (size_t)t * H_DIM);
    ushort4* o = (ushort4*)(xbig + (size_t)t * KBIG);
#pragma unroll
    for (int p = 0; p < 4; ++p) {
      float4 v = xr[p * 256 + tid];
      ushort4 u;
      u.x = f2bf(v.x); u.y = f2bf(v.y); u.z = f2bf(v.z); u.w = f2bf(v.w);
      o[p * 256 + tid] = u;
    }
  } else if (b < WT_BLOCKS + CX_BLOCKS + TA_BLOCKS) {
    // ---- A transpose: adapter a, 128 h-rows
    const int bb = b - (WT_BLOCKS + CX_BLOCKS);
    const int a = bb >> 5;
    const int h0 = (bb & 31) * 128;
    float (*t)[49] = (float(*)[49])smem;
    const float* src = A + ((size_t)a * H_DIM + h0) * 48;
#pragma unroll
    for (int e = 0; e < 24; ++e) {
      int idx = e * 256 + tid;            // 0..6143
      t[idx / 48][idx % 48] = src[idx];
    }
    __syncthreads();
#pragma unroll
    for (int e = 0; e < 24; ++e) {
      int idx = e * 256 + tid;
      int j = idx >> 7;                   // 0..47
      int c = idx & 127;
      AT[(size_t)(a * 48 + j) * H_DIM + h0 + c] = f2bf(t[c][j]);
    }
  } else {
    // ---- Bfull ext columns: 8 n-rows per block (3072 elems, 12/thread)
    const int bb = b - (WT_BLOCKS + CX_BLOCKS + TA_BLOCKS);
#pragma unroll
    for (int e = 0; e < 12; ++e) {
      int idx = e * 256 + tid;            // 0..3071
      int n = bb * 8 + (idx / 384);
      int c = idx % 384;
      int a = c / 48, j = c % 48;
      float v = 0.0f;
      if (j < 16) {
        if (n < 4096) v = Bq[(size_t)(a * RANK + j) * 4096 + n];
      } else if (j < 32) {
        if (n >= 4096 && n < 8192) v = Bkv[(size_t)(a * RANK + (j - 16)) * 8192 + (n - 4096)];
      } else {
        if (n >= 8192) v = Bkv[(size_t)(a * RANK + (j - 32)) * 8192 + (n - 4096)];
      }
      WbigT[(size_t)n * KBIG + H_DIM + c] = f2bf(v);
    }
  }
}

// ---------------------------------------------------------------------------
// K2b: xa_all = x @ A_all  (M=4096, N=384, K=4096), epilogue scatters
// per-token adapter selection into xbig ext columns.
// 128x64 tile -> grid (6,32)=192 blocks (R8-proven 45us).
__global__ __launch_bounds__(256) void xa_gemm_scatter(
    const unsigned short* __restrict__ Xb, const unsigned short* __restrict__ AT,
    const int* __restrict__ widx, unsigned short* __restrict__ xbig) {
  __shared__ __align__(16) unsigned char lds[16384 + 8192];  // As 128x64, Bs 64x64
  const int tid = threadIdx.x;
  const int w = tid >> 6, l = tid & 63;
  const int wm = w >> 1, wn = w & 1;
  const int lr = l & 15, hi = l >> 4;
  const int innsw = (lr & 7) << 4;
  const int m0 = blockIdx.y * 128;   // token tile
  const int n0 = blockIdx.x * 64;    // j tile

  f32x4 acc[4][2];
  const f32x4 fzero = {0.f, 0.f, 0.f, 0.f};
#pragma unroll
  for (int mf = 0; mf < 4; ++mf)
#pragma unroll
    for (int nf = 0; nf < 2; ++nf) acc[mf][nf] = fzero;

  for (int kt = 0; kt < H_DIM / 64; ++kt) {
    __syncthreads();
    const int kb = kt * 64;
#pragma unroll
    for (int ld = 0; ld < 4; ++ld) {
      int d = (ld * 256 + tid) * 16;
      int row = d >> 7;
      int colb = (d & 127) ^ ((row & 7) << 4);
      gload_lds16((const char*)Xb + (size_t)(m0 + row) * (KBIG * 2) + kb * 2 + colb,
                  &lds[d]);
    }
#pragma unroll
    for (int ld = 0; ld < 2; ++ld) {
      int d = (ld * 256 + tid) * 16;
      int row = d >> 7;
      int colb = (d & 127) ^ ((row & 7) << 4);
      gload_lds16((const char*)AT + (size_t)(n0 + row) * (H_DIM * 2) + kb * 2 + colb,
                  &lds[16384 + d]);
    }
    __syncthreads();
#pragma unroll
    for (int kk = 0; kk < 2; ++kk) {
      bf16x8 af[4], bfr[2];
#pragma unroll
      for (int mf = 0; mf < 4; ++mf)
        af[mf] = *(const bf16x8*)(lds + (wm * 64 + mf * 16 + lr) * 128 +
                                  ((kk * 64 + hi * 16) ^ innsw));
#pragma unroll
      for (int nf = 0; nf < 2; ++nf)
        bfr[nf] = *(const bf16x8*)(lds + 16384 + (wn * 32 + nf * 16 + lr) * 128 +
                                   ((kk * 64 + hi * 16) ^ innsw));
#pragma unroll
      for (int mf = 0; mf < 4; ++mf)
#pragma unroll
        for (int nf = 0; nf < 2; ++nf)
          acc[mf][nf] = __builtin_amdgcn_mfma_f32_16x16x32_bf16(
              af[mf], bfr[nf], acc[mf][nf], 0, 0, 0);
    }
  }
  // scatter epilogue: keep only the token's own adapter block, else 0
  const int r4 = hi * 4;
#pragma unroll
  for (int mf = 0; mf < 4; ++mf)
#pragma unroll
    for (int r = 0; r < 4; ++r) {
      const int t = m0 + wm * 64 + mf * 16 + r4 + r;
      const int a = widx[t];
#pragma unroll
      for (int nf = 0; nf < 2; ++nf) {
        const int col = n0 + wn * 32 + nf * 16 + lr;   // j in [0,384)
        float v = (col / 48 == a) ? acc[mf][nf][r] : 0.0f;
        xbig[(size_t)t * KBIG + H_DIM + col] = f2bf(v);
      }
    }
}

// ---------------------------------------------------------------------------
// K3: 256x256-tile bf16 GEMM, 2 barriers per K-tile (R5/R8 proven skeleton)
// + DEEP PREFETCH via in-place half-slot rotation (m201-depth slack):
// half h(t+2) is staged into buf[t&1].h one barrier after h(t)'s reads
// retire, so every half lands >=1.5 K-tiles before its read.
// Stage issue points: H1(t): B1(t+1),A1(t+1); H2(t): A0(t+2),B0(t+2).
// FIFO-derived waits (12 loads steady, never drained): vmcnt(6)@H1-top
// (A0,B0,B1 of t landed), vmcnt(8)@H2-top (A1 of t landed).
// WAR safe: each in-place stage issues >=1 barrier after all waves' reads
// of the old copy (lgkm drains before MFMA before barrier).
// XCD 8x12 rectangle swizzle (FETCH 900->323 MB, R11-verified).
__global__ __launch_bounds__(512, 2) void gemm_bf16_8ph(
    const unsigned short* __restrict__ Xb, const unsigned short* __restrict__ Wt,
    float* __restrict__ out) {
  __shared__ __align__(16) unsigned char lds[2 * 2 * 2 * 16384];  // 128 KiB

  const int tid = threadIdx.x;
  const int w   = tid >> 6;
  const int l   = tid & 63;
  const int wm  = w >> 2;        // 0..1
  const int wn  = w & 3;         // 0..3
  const int lr  = l & 15;
  const int hi  = l >> 4;
  const int innsw = (lr & 7) << 4;   // read-side XOR swizzle bits

  // XCD 8x12 rectangle swizzle: xcd r -> rect (r>>2, r&3); local col-major
  const int id  = blockIdx.x;
  const int r8  = id & 7;            // XCD
  const int loc = id >> 3;           // 0..95
  const int lm  = loc & 7;           // 0..7  (bm within rect)
  const int ln  = loc >> 3;          // 0..11 (bn within rect)
  const int bm  = (r8 >> 2) * 8 + lm;
  const int bn  = (r8 & 3) * 12 + ln;
  const int m0 = bm * 256, n0 = bn * 256;

  auto stage = [&](int buf, int ab, int half, const unsigned short* G,
                   int row0, int kb) {
    unsigned char* lb = &lds[((((buf << 1) | ab) << 1) | half) * 16384];
    const char* gb = (const char*)G;
#pragma unroll
    for (int ld = 0; ld < 2; ++ld) {
      int d = (ld * 512 + tid) * 16;            // linear LDS dest byte
      int row = d >> 7;                          // 0..127
      int colb = (d & 127) ^ ((row & 7) << 4);   // swizzled source col (bytes)
      gload_lds16(gb + (size_t)(row0 + row) * (KBIG * 2) + kb * 2 + colb,
                  lb + d);
    }
  };
  auto readA = [&](int buf, int mq, int mf, int kk) -> bf16x8 {
    const unsigned char* lb = &lds[((((buf << 1) | 0) << 1) | mq) * 16384];
    int ph = (wm * 64 + mf * 16 + lr) * 128 + ((kk * 64 + hi * 16) ^ innsw);
    return *(const bf16x8*)(lb + ph);
  };
  auto readB = [&](int buf, int nq, int nf, int kk) -> bf16x8 {
    const unsigned char* lb = &lds[((((buf << 1) | 1) << 1) | nq) * 16384];
    int ph = (wn * 32 + nf * 16 + lr) * 128 + ((kk * 64 + hi * 16) ^ innsw);
    return *(const bf16x8*)(lb + ph);
  };

  f32x4 acc[4][4][2];   // [quad][mf][nf]
  const f32x4 fzero = {0.f, 0.f, 0.f, 0.f};
#pragma unroll
  for (int q = 0; q < 4; ++q)
#pragma unroll
    for (int mf = 0; mf < 4; ++mf)
#pragma unroll
      for (int nf = 0; nf < 2; ++nf) acc[q][mf][nf] = fzero;

  bf16x8 a_[4][2];   // current A-half fragments (A0 in H1, A1 in H2)
  bf16x8 b0_[2][2];  // B half 0 fragments (live whole iter)
  bf16x8 b1_[2][2];  // B half 1 fragments (live whole iter)

#define MFMA_QUAD(Q, BSRC)                                                   \
    _Pragma("unroll") for (int kk = 0; kk < 2; ++kk)                         \
      _Pragma("unroll") for (int mf = 0; mf < 4; ++mf)                       \
        _Pragma("unroll") for (int nf = 0; nf < 2; ++nf)                     \
          acc[Q][mf][nf] = __builtin_amdgcn_mfma_f32_16x16x32_bf16(          \
              a_[mf][kk], BSRC[nf][kk], acc[Q][mf][nf], 0, 0, 0)

  // prologue: tile 0 halves A0,B0,B1,A1 into buf0; A0,B0 of tile 1 into buf1
  // (12 loads outstanding — matches steady-state queue)
  stage(0, 0, 0, Xb, m0,       0);
  stage(0, 1, 0, Wt, n0,       0);
  stage(0, 1, 1, Wt, n0 + 128, 0);
  stage(0, 0, 1, Xb, m0 + 128, 0);
  stage(1, 0, 0, Xb, m0,       64);
  stage(1, 1, 0, Wt, n0,       64);

  for (int t = 0; t < NT; ++t) {
    const int cur = t & 1, nxt = cur ^ 1;
    const int kb1 = ((t + 1 < NT) ? (t + 1) : t) * 64;   // for B1/A1 of t+1
    const int kb2 = ((t + 2 < NT) ? (t + 2) : t) * 64;   // for A0/B0 of t+2

    // H1 top: A0,B0,B1 of tile t landed (retire 6, keep 6)
    asm volatile("s_waitcnt vmcnt(6)" ::: "memory");
    __builtin_amdgcn_s_barrier();

    // H1: read A0,B0,B1(cur); stage B1(t+1),A1(t+1) -> buf[nxt];
    //     quads (M0,N0)+(M0,N1)
#pragma unroll
    for (int mf = 0; mf < 4; ++mf)
#pragma unroll
      for (int kk = 0; kk < 2; ++kk) a_[mf][kk] = readA(cur, 0, mf, kk);
#pragma unroll
    for (int nf = 0; nf < 2; ++nf)
#pragma unroll
      for (int kk = 0; kk < 2; ++kk) b0_[nf][kk] = readB(cur, 0, nf, kk);
#pragma unroll
    for (int nf = 0; nf < 2; ++nf)
#pragma unroll
      for (int kk = 0; kk < 2; ++kk) b1_[nf][kk] = readB(cur, 1, nf, kk);
    stage(nxt, 1, 1, Wt, n0 + 128, kb1);
    stage(nxt, 0, 1, Xb, m0 + 128, kb1);
    __builtin_amdgcn_s_setprio(1);
    MFMA_QUAD(0, b0_);
    MFMA_QUAD(1, b1_);
    __builtin_amdgcn_s_setprio(0);

    // H2 top: A1 of tile t landed (retire 2, keep 8)
    asm volatile("s_waitcnt vmcnt(8)" ::: "memory");
    __builtin_amdgcn_s_barrier();

    // H2: read A1(cur); stage A0(t+2),B0(t+2) IN-PLACE into buf[cur]
    //     (A0/B0(t) slots — reads retired at H1, ordered by the H2 barrier);
    //     quads (M1,N1)+(M1,N0)
#pragma unroll
    for (int mf = 0; mf < 4; ++mf)
#pragma unroll
      for (int kk = 0; kk < 2; ++kk) a_[mf][kk] = readA(cur, 1, mf, kk);
    stage(cur, 0, 0, Xb, m0, kb2);
    stage(cur, 1, 0, Wt, n0, kb2);
    __builtin_amdgcn_s_setprio(1);
    MFMA_QUAD(2, b1_);
    MFMA_QUAD(3, b0_);
    __builtin_amdgcn_s_setprio(0);
  }
#undef MFMA_QUAD

  // epilogue: C/D mapping col = lane&15, row = (lane>>4)*4 + reg
  const int r4 = hi * 4;
  constexpr int QM[4] = {0, 0, 1, 1};
  constexpr int QN[4] = {0, 1, 1, 0};
#pragma unroll
  for (int q = 0; q < 4; ++q)
#pragma unroll
    for (int mf = 0; mf < 4; ++mf)
#pragma unroll
      for (int nf = 0; nf < 2; ++nf) {
        const int row = m0 + QM[q] * 128 + wm * 64 + mf * 16 + r4;
        const int col = n0 + QN[q] * 128 + wn * 32 + nf * 16 + lr;
#pragma unroll
        for (int r = 0; r < 4; ++r)
          out[(size_t)(row + r) * NOUT + col] = acc[q][mf][nf][r];
      }
}

// ---------------------------------------------------------------------------
extern "C" void kernel_launch(void* const* d_in, const int* in_sizes, int n_in,
                              void* d_out, int out_size, void* d_ws, size_t ws_size,
                              hipStream_t stream) {
  const float* x    = (const float*)d_in[0];
  const int*   widx = (const int*)d_in[1];
  const float* W    = (const float*)d_in[2];
  const float* Aq   = (const float*)d_in[3];
  const float* Bq   = (const float*)d_in[4];
  const float* Bkv  = (const float*)d_in[5];
  float* out = (float*)d_out;

  unsigned short* xbig  = (unsigned short*)d_ws;
  unsigned short* WbigT = (unsigned short*)((char*)d_ws + (size_t)S_TOK * KBIG * 2);
  unsigned short* AT    = (unsigned short*)((char*)d_ws + (size_t)S_TOK * KBIG * 2
                                            + (size_t)NOUT * KBIG * 2);

  hipLaunchKernelGGL(prep_fused, dim3(WT_BLOCKS + CX_BLOCKS + TA_BLOCKS + BF_BLOCKS),
                     dim3(256), 0, stream, W, x, Aq, Bq, Bkv, WbigT, xbig, AT);
  hipLaunchKernelGGL(xa_gemm_scatter, dim3(6, S_TOK / 128), dim3(256), 0, stream,
                     xbig, AT, widx, xbig);
  hipLaunchKernelGGL(gemm_bf16_8ph, dim3(768), dim3(512), 0, stream, xbig, WbigT, out);
}